// Round 12
// baseline (180.405 us; speedup 1.0000x reference)
//
#include <hip/hip_runtime.h>
#include <math.h>

#define L_SEQ 2048
#define DM 1024
#define DI 2048
#define DS 16
#define DTR 64
#define EPS 1e-5f
#define NSEG 32
#define SEGLEN 64
#define NSTATE (DI * DS)

typedef float f32x4 __attribute__((ext_vector_type(4)));
typedef __bf16 bf16x8 __attribute__((ext_vector_type(8)));
typedef _Float16 h16x2 __attribute__((ext_vector_type(2)));

static __device__ __forceinline__ unsigned short f2bf(float f) {
  union { float f; unsigned u; } v; v.f = f;
  unsigned r = v.u + 0x7fffu + ((v.u >> 16) & 1u);
  return (unsigned short)(r >> 16);
}
static __device__ __forceinline__ float bf2f(unsigned short s) {
  union { unsigned u; float f; } v; v.u = ((unsigned)s) << 16;
  return v.f;
}

// global -> LDS direct copy, 16B per lane (wave-uniform LDS base).
static __device__ __forceinline__ void gload16(const void* g, void* l) {
  __builtin_amdgcn_global_load_lds(
      (__attribute__((address_space(1))) void*)(unsigned long long)(g),
      (__attribute__((address_space(3))) void*)(unsigned)(unsigned long long)(l),
      16, 0, 0);
}

// ---------------- shared transpose tile: W[K][N] fp32 -> Wt[N][K] bf16 ----------------
static __device__ __forceinline__ void trans_tile(
    const float* __restrict__ W, unsigned short* __restrict__ Wt,
    int K, int N, int n0, int k0)
{
  __shared__ unsigned short s[64][80];
  int tid = threadIdx.x;
  #pragma unroll
  for (int p = 0; p < 4; ++p) {
    int i = p * 16 + (tid >> 4);
    int j = (tid & 15) * 4;
    float4 w = *(const float4*)&W[(size_t)(k0 + i) * N + n0 + j];
    s[j + 0][i] = f2bf(w.x); s[j + 1][i] = f2bf(w.y);
    s[j + 2][i] = f2bf(w.z); s[j + 3][i] = f2bf(w.w);
  }
  __syncthreads();
  #pragma unroll
  for (int q = 0; q < 2; ++q) {
    int n = q * 32 + (tid >> 3);
    int i8 = (tid & 7) * 8;
    *(int4*)&Wt[(size_t)(n0 + n) * K + k0 + i8] = *(const int4*)&s[n][i8];
  }
}

// ---------------- merged prep: LN + Wtin + Wtout + Wdt_t + Wxt in ONE launch ----------------
// regions: [0,2048) LN rows; [2048,3072) Wtin; [3072,3584) Wtout;
// [3584,3616) Wdt_t; [3616,3632) Wxt elementwise.
__global__ __launch_bounds__(256) void prep_all(
    const float* __restrict__ x, const float* __restrict__ ln_s,
    const float* __restrict__ ln_b, unsigned short* __restrict__ xnb,
    const float* __restrict__ W_in, const float* __restrict__ W_out,
    const float* __restrict__ W_dt, const float* __restrict__ Wx,
    unsigned short* __restrict__ Wtin, unsigned short* __restrict__ Wtout,
    unsigned short* __restrict__ Wdt_t, unsigned short* __restrict__ Wxt)
{
  int b = blockIdx.x;
  int t = threadIdx.x;
  if (b < 2048) {
    // LayerNorm row -> bf16
    __shared__ float red[8];
    int row = b;
    float4 xv = ((const float4*)(x + (size_t)row * DM))[t];
    float s  = xv.x + xv.y + xv.z + xv.w;
    float s2 = xv.x*xv.x + xv.y*xv.y + xv.z*xv.z + xv.w*xv.w;
    #pragma unroll
    for (int m = 32; m >= 1; m >>= 1) {
      s  += __shfl_xor(s, m);
      s2 += __shfl_xor(s2, m);
    }
    int wid = t >> 6, lane = t & 63;
    if (lane == 0) { red[wid] = s; red[4 + wid] = s2; }
    __syncthreads();
    s  = red[0] + red[1] + red[2] + red[3];
    s2 = red[4] + red[5] + red[6] + red[7];
    float mu = s * (1.f / DM);
    float var = s2 * (1.f / DM) - mu * mu;
    float rs = rsqrtf(var + EPS);
    float4 sc4 = ((const float4*)ln_s)[t];
    float4 bi4 = ((const float4*)ln_b)[t];
    ushort4 ob;
    ob.x = f2bf((xv.x - mu) * rs * sc4.x + bi4.x);
    ob.y = f2bf((xv.y - mu) * rs * sc4.y + bi4.y);
    ob.z = f2bf((xv.z - mu) * rs * sc4.z + bi4.z);
    ob.w = f2bf((xv.w - mu) * rs * sc4.w + bi4.w);
    *(ushort4*)&xnb[(size_t)row * DM + t * 4] = ob;
  } else if (b < 3072) {
    int r = b - 2048;
    trans_tile(W_in, Wtin, DM, 2 * DI, (r & 63) * 64, (r >> 6) * 64);
  } else if (b < 3584) {
    int r = b - 3072;
    trans_tile(W_out, Wtout, DI, DM, (r & 15) * 64, (r >> 4) * 64);
  } else if (b < 3616) {
    int r = b - 3584;
    trans_tile(W_dt, Wdt_t, DTR, DI, r * 64, 0);
  } else {
    int r = b - 3616;
    int i = r * 256 + t;                    // over 128*2048 / 16 blocks
    #pragma unroll
    for (int p = 0; p < 64; ++p) {
      int ii = i + p * 4096;
      int n = ii >> 11, k = ii & 2047;
      Wxt[ii] = (n < 96) ? f2bf(Wx[(size_t)k * 96 + n]) : (unsigned short)0;
    }
  }
}

// ---------------- bf16 MFMA GEMM v2 ----------------
// OUTB=1: bf16 C staged through LDS for coalesced int4 writes.
// EPI: 0 none, 1 softplus(acc + bias[row]), 2 acc + R[row][col] (fp32 out only)
template<int BM, int BN, int EPI, int OUTB, int SPLITK>
__global__ __launch_bounds__(256) void gemm2(
    const unsigned short* __restrict__ A, int lda,
    const unsigned short* __restrict__ Bt, int ldb,
    void* __restrict__ Cv, int ldc,
    int M, int N, int K,
    const float* __restrict__ bias,
    const float* __restrict__ R, int ldr)
{
  constexpr int WM = BM / 2, WN = BN / 2;
  constexpr int FM = WM / 16, FN = WN / 16;
  __shared__ __align__(16) unsigned short sm[(BM + BN) * 64];
  unsigned short* smA = sm;
  unsigned short* smB = sm + BM * 64;

  int nwg = gridDim.x * gridDim.y;
  int bid = blockIdx.y * gridDim.x + blockIdx.x;
  if ((nwg & 7) == 0) {
    int cpx = nwg >> 3;
    bid = (bid & 7) * cpx + (bid >> 3);
  }
  int bx = bid % gridDim.x;
  int by = bid / gridDim.x;
  int m0 = by * BM, n0 = bx * BN;

  int tid = threadIdx.x;
  int lane = tid & 63, wid = tid >> 6;
  int wm = wid >> 1, wn = wid & 1;

  int kb = blockIdx.z * (K / SPLITK);
  int nt = (K / SPLITK) / 64;

  int rs = lane >> 3;
  int cs = (lane & 7) * 8;

  f32x4 acc[FM][FN];
  #pragma unroll
  for (int m = 0; m < FM; ++m)
    #pragma unroll
    for (int n = 0; n < FN; ++n) acc[m][n] = (f32x4){0.f, 0.f, 0.f, 0.f};

  for (int kt = 0; kt < nt; ++kt) {
    __syncthreads();
    #pragma unroll
    for (int i = 0; i < BM / 32; ++i) {
      int chunk = wid * (BM / 32) + i;
      gload16(A + (size_t)(m0 + chunk * 8 + rs) * lda + kb + kt * 64 + cs,
              (char*)smA + chunk * 1024);
    }
    #pragma unroll
    for (int i = 0; i < BN / 32; ++i) {
      int chunk = wid * (BN / 32) + i;
      gload16(Bt + (size_t)(n0 + chunk * 8 + rs) * ldb + kb + kt * 64 + cs,
              (char*)smB + chunk * 1024);
    }
    __syncthreads();

    #pragma unroll
    for (int kk = 0; kk < 2; ++kk) {
      bf16x8 aF[FM], bF[FN];
      #pragma unroll
      for (int m = 0; m < FM; ++m) {
        int r = wm * WM + m * 16 + (lane & 15);
        aF[m] = *(const bf16x8*)((const char*)smA + r * 128 + kk * 64 + (lane >> 4) * 16);
      }
      #pragma unroll
      for (int n = 0; n < FN; ++n) {
        int r = wn * WN + n * 16 + (lane & 15);
        bF[n] = *(const bf16x8*)((const char*)smB + r * 128 + kk * 64 + (lane >> 4) * 16);
      }
      #pragma unroll
      for (int m = 0; m < FM; ++m)
        #pragma unroll
        for (int n = 0; n < FN; ++n)
          acc[m][n] = __builtin_amdgcn_mfma_f32_16x16x32_bf16(
              aF[m], bF[n], acc[m][n], 0, 0, 0);
    }
  }

  int cm = (lane >> 4) * 4, cn = lane & 15;
  if (OUTB) {
    unsigned short* Cb = (unsigned short*)Cv;
    __syncthreads();
    #pragma unroll
    for (int m = 0; m < FM; ++m)
      #pragma unroll
      for (int n = 0; n < FN; ++n) {
        int col = wn * WN + n * 16 + cn;
        #pragma unroll
        for (int r = 0; r < 4; ++r) {
          int row = wm * WM + m * 16 + cm + r;
          float v = acc[m][n][r];
          if (EPI == 1) {
            float w = v + bias[m0 + row];
            v = (w > 20.f) ? w : log1pf(__expf(w));
          }
          sm[row * BN + col] = f2bf(v);
        }
      }
    __syncthreads();
    constexpr int NI4 = BM * BN / 8;
    for (int k = tid; k < NI4; k += 256) {
      int row = k / (BN / 8);
      int c8 = (k % (BN / 8)) * 8;
      *(int4*)&Cb[(size_t)(m0 + row) * ldc + n0 + c8] = *(const int4*)&sm[row * BN + c8];
    }
  } else {
    float* Cf = (float*)Cv + (size_t)blockIdx.z * M * ldc;
    #pragma unroll
    for (int m = 0; m < FM; ++m)
      #pragma unroll
      for (int n = 0; n < FN; ++n) {
        int col = n0 + wn * WN + n * 16 + cn;
        #pragma unroll
        for (int r = 0; r < 4; ++r) {
          int row = m0 + wm * WM + m * 16 + cm + r;
          float v = acc[m][n][r];
          if (EPI == 1) {
            float w = v + bias[row];
            v = (w > 20.f) ? w : log1pf(__expf(w));
          }
          if (EPI == 2) v += R[(size_t)row * ldr + col];
          Cf[(size_t)row * ldc + col] = v;
        }
      }
  }
}

// ---------------- split-K reduce: part[8][2048*128] fp32 -> xdbl bf16 ----------------
__global__ __launch_bounds__(256) void xdbl_reduce(
    const float* __restrict__ part, unsigned short* __restrict__ xdbl)
{
  int i = (blockIdx.x * 256 + threadIdx.x) * 4;
  const int SL = 2048 * 128;
  float4 s = *(const float4*)&part[i];
  #pragma unroll
  for (int z = 1; z < 8; ++z) {
    float4 p = *(const float4*)&part[(size_t)z * SL + i];
    s.x += p.x; s.y += p.y; s.z += p.z; s.w += p.w;
  }
  ushort4 ob;
  ob.x = f2bf(s.x); ob.y = f2bf(s.y); ob.z = f2bf(s.z); ob.w = f2bf(s.w);
  *(ushort4*)&xdbl[i] = ob;
}

// ---------------- causal conv4 + SiLU, dual-layout output ----------------
__global__ __launch_bounds__(256) void conv_silu_fused(
    const unsigned short* __restrict__ xrT,
    const float* __restrict__ Wc, const float* __restrict__ bc,
    unsigned short* __restrict__ u2T, unsigned short* __restrict__ u2b)
{
  __shared__ unsigned short st[128][68];   // [l][d] tile
  int d0 = blockIdx.x * 64, l0 = blockIdx.y * 128;
  int tid = threadIdx.x;
  int dloc = tid & 63;
  int lp = (tid >> 6) * 32;
  int d = d0 + dloc;
  const unsigned short* ur = xrT + (size_t)d * L_SEQ + l0 + lp;
  float w0 = Wc[0 * DI + d], w1 = Wc[1 * DI + d];
  float w2 = Wc[2 * DI + d], w3 = Wc[3 * DI + d];
  float b = bc[d];

  ushort4 vin[8];
  #pragma unroll
  for (int j = 0; j < 8; ++j) vin[j] = *(const ushort4*)&ur[j * 4];
  ushort4 vh; vh.x = vh.y = vh.z = vh.w = 0;
  if (l0 + lp > 0) vh = *(const ushort4*)&ur[-4];
  float prev3 = bf2f(vh.y), prev2 = bf2f(vh.z), prev1 = bf2f(vh.w);

  #pragma unroll
  for (int j = 0; j < 8; ++j) {
    float xs[4] = {bf2f(vin[j].x), bf2f(vin[j].y), bf2f(vin[j].z), bf2f(vin[j].w)};
    ushort4 ob;
    unsigned short* o = (unsigned short*)&ob;
    #pragma unroll
    for (int i = 0; i < 4; ++i) {
      float y = b + w0 * prev3 + w1 * prev2 + w2 * prev1 + w3 * xs[i];
      prev3 = prev2; prev2 = prev1; prev1 = xs[i];
      float sig = 1.f / (1.f + __expf(-y));
      o[i] = f2bf(y * sig);
    }
    *(ushort4*)&u2T[(size_t)d * L_SEQ + l0 + lp + j * 4] = ob;
    st[lp + j * 4 + 0][dloc] = o[0];
    st[lp + j * 4 + 1][dloc] = o[1];
    st[lp + j * 4 + 2][dloc] = o[2];
    st[lp + j * 4 + 3][dloc] = o[3];
  }
  __syncthreads();
  int lr = tid >> 1, hf = (tid & 1) * 32;
  unsigned short* ob = &u2b[(size_t)(l0 + lr) * DI + d0 + hf];
  *(int4*)&ob[0]  = *(const int4*)&st[lr][hf + 0];
  *(int4*)&ob[8]  = *(const int4*)&st[lr][hf + 8];
  *(int4*)&ob[16] = *(const int4*)&st[lr][hf + 16];
  *(int4*)&ob[24] = *(const int4*)&st[lr][hf + 24];
}

// ================= segmented selective scan =================

__global__ __launch_bounds__(128) void scan_pass1(
    const unsigned short* __restrict__ deltaT, const unsigned short* __restrict__ u2T,
    const unsigned short* __restrict__ xdbl,
    const float* __restrict__ A_log,
    float* __restrict__ hend, float* __restrict__ aprod)
{
  int t = threadIdx.x;
  int ch = t >> 4, n = t & 15;
  int li = (t & 15) * 4;
  int d0 = blockIdx.x * 8, d = d0 + ch;
  int base = blockIdx.y * SEGLEN;

  __shared__ __align__(16) float sdT[8][68], suT[8][68], sBT[16][68];

  float An = -__expf(A_log[d * DS + n]);

  ushort4 rdu = *(const ushort4*)&deltaT[(size_t)d * L_SEQ + base + li];
  ushort4 ru  = *(const ushort4*)&u2T[(size_t)d * L_SEQ + base + li];
  ushort4 rB[2];
  #pragma unroll
  for (int q = 0; q < 2; ++q) {
    int ll = base + (t >> 2) + q * 32;
    rB[q] = *(const ushort4*)&xdbl[(size_t)ll * 128 + 64 + (t & 3) * 4];
  }

  float d0v = bf2f(rdu.x), d1v = bf2f(rdu.y), d2v = bf2f(rdu.z), d3v = bf2f(rdu.w);
  sdT[ch][li + 0] = d0v; sdT[ch][li + 1] = d1v;
  sdT[ch][li + 2] = d2v; sdT[ch][li + 3] = d3v;
  suT[ch][li + 0] = d0v * bf2f(ru.x); suT[ch][li + 1] = d1v * bf2f(ru.y);
  suT[ch][li + 2] = d2v * bf2f(ru.z); suT[ch][li + 3] = d3v * bf2f(ru.w);
  #pragma unroll
  for (int q = 0; q < 2; ++q) {
    int ll = (t >> 2) + q * 32;
    int nb = (t & 3) * 4;
    sBT[nb + 0][ll] = bf2f(rB[q].x); sBT[nb + 1][ll] = bf2f(rB[q].y);
    sBT[nb + 2][ll] = bf2f(rB[q].z); sBT[nb + 3][ll] = bf2f(rB[q].w);
  }
  __syncthreads();

  float h = 0.f, sdl = 0.f;
  #pragma unroll
  for (int g = 0; g < 64; g += 4) {
    float4 dl4 = *(const float4*)&sdT[ch][g];
    float4 du4 = *(const float4*)&suT[ch][g];
    float4 Bn4 = *(const float4*)&sBT[n][g];
    float dl[4] = {dl4.x, dl4.y, dl4.z, dl4.w};
    float du[4] = {du4.x, du4.y, du4.z, du4.w};
    float Bn[4] = {Bn4.x, Bn4.y, Bn4.z, Bn4.w};
    #pragma unroll
    for (int i = 0; i < 4; ++i) {
      float dA = __expf(dl[i] * An);
      sdl += dl[i];
      h = dA * h + du[i] * Bn[i];
    }
  }
  size_t idx = (size_t)blockIdx.y * NSTATE + d0 * DS + t;
  hend[idx]  = h;
  aprod[idx] = __expf(An * sdl);   // prod of exp == exp of sum
}

// ---- pass 2: prefix over segment summaries -> h_in ----
__global__ __launch_bounds__(256) void scan_pass2(
    const float* __restrict__ hend, const float* __restrict__ aprod,
    float* __restrict__ h_in)
{
  int i = blockIdx.x * 256 + threadIdx.x;
  float h = 0.f;
  h_in[i] = 0.f;
  for (int s = 0; s < NSEG - 1; ++s) {
    h = aprod[(size_t)s * NSTATE + i] * h + hend[(size_t)s * NSTATE + i];
    h_in[(size_t)(s + 1) * NSTATE + i] = h;
  }
}

// ---- pass 3: full scan per segment; writes yb [l][di] directly ----
__global__ __launch_bounds__(128) void scan_pass3(
    const unsigned short* __restrict__ deltaT, const unsigned short* __restrict__ u2T,
    const unsigned short* __restrict__ resT,
    const unsigned short* __restrict__ xdbl,
    const float* __restrict__ A_log, const float* __restrict__ Dp,
    const float* __restrict__ h_in,
    unsigned short* __restrict__ yb)
{
  int t = threadIdx.x;
  int ch = t >> 4, n = t & 15;
  int li = (t & 15) * 4;
  int d0 = blockIdx.x * 8, d = d0 + ch;
  int s = blockIdx.y;
  int base = s * SEGLEN;

  __shared__ __align__(16) float sdT[8][68], suT[8][68];
  __shared__ __align__(16) float sBT[16][68], sCT[16][68];
  __shared__ __align__(4) _Float16 svh[32][134];
  __shared__ __align__(16) unsigned short syt[32][8];

  float An = -__expf(A_log[d * DS + n]);
  float h = h_in[(size_t)s * NSTATE + d0 * DS + t];

  ushort4 rdu = *(const ushort4*)&deltaT[(size_t)d * L_SEQ + base + li];
  ushort4 ru  = *(const ushort4*)&u2T[(size_t)d * L_SEQ + base + li];
  ushort4 rB[2], rC[2];
  #pragma unroll
  for (int q = 0; q < 2; ++q) {
    int ll = base + (t >> 2) + q * 32;
    int n4 = (t & 3) * 4;
    rB[q] = *(const ushort4*)&xdbl[(size_t)ll * 128 + 64 + n4];
    rC[q] = *(const ushort4*)&xdbl[(size_t)ll * 128 + 80 + n4];
  }

  float d0v = bf2f(rdu.x), d1v = bf2f(rdu.y), d2v = bf2f(rdu.z), d3v = bf2f(rdu.w);
  sdT[ch][li + 0] = d0v; sdT[ch][li + 1] = d1v;
  sdT[ch][li + 2] = d2v; sdT[ch][li + 3] = d3v;
  suT[ch][li + 0] = d0v * bf2f(ru.x); suT[ch][li + 1] = d1v * bf2f(ru.y);
  suT[ch][li + 2] = d2v * bf2f(ru.z); suT[ch][li + 3] = d3v * bf2f(ru.w);
  #pragma unroll
  for (int q = 0; q < 2; ++q) {
    int ll = (t >> 2) + q * 32;
    int nb = (t & 3) * 4;
    sBT[nb + 0][ll] = bf2f(rB[q].x); sBT[nb + 1][ll] = bf2f(rB[q].y);
    sBT[nb + 2][ll] = bf2f(rB[q].z); sBT[nb + 3][ll] = bf2f(rB[q].w);
    sCT[nb + 0][ll] = bf2f(rC[q].x); sCT[nb + 1][ll] = bf2f(rC[q].y);
    sCT[nb + 2][ll] = bf2f(rC[q].z); sCT[nb + 3][ll] = bf2f(rC[q].w);
  }
  __syncthreads();

  #pragma unroll
  for (int half = 0; half < 2; ++half) {
    int g0 = half * 32;
    #pragma unroll
    for (int g = g0; g < g0 + 32; g += 4) {
      float4 dl4 = *(const float4*)&sdT[ch][g];
      float4 du4 = *(const float4*)&suT[ch][g];
      float4 Bn4 = *(const float4*)&sBT[n][g];
      float4 Cn4 = *(const float4*)&sCT[n][g];
      float dl[4] = {dl4.x, dl4.y, dl4.z, dl4.w};
      float du[4] = {du4.x, du4.y, du4.z, du4.w};
      float Bn[4] = {Bn4.x, Bn4.y, Bn4.z, Bn4.w};
      float Cn[4] = {Cn4.x, Cn4.y, Cn4.z, Cn4.w};
      #pragma unroll
      for (int i = 0; i < 4; ++i) {
        float dA = __expf(dl[i] * An);
        h = dA * h + du[i] * Bn[i];
        svh[g - g0 + i][t] = (_Float16)(h * Cn[i]);
      }
    }
    __syncthreads();

    #pragma unroll
    for (int r = 0; r < 2; ++r) {
      int idx = r * 128 + t;
      int ll = idx & 31, c2 = idx >> 5;
      const _Float16* row = &svh[ll][c2 * 16];
      float sum = 0.f;
      #pragma unroll
      for (int k = 0; k < 8; ++k) {
        h16x2 pv = *(const h16x2*)&row[k * 2];
        sum += (float)pv.x + (float)pv.y;
      }
      int dd = d0 + c2;
      int lg = base + g0 + ll;
      float uv = bf2f(u2T[(size_t)dd * L_SEQ + lg]);
      float rv = bf2f(resT[(size_t)dd * L_SEQ + lg]);
      float sig = 1.f / (1.f + __expf(-rv));
      syt[ll][c2] = f2bf((sum + uv * Dp[dd]) * rv * sig);
    }
    __syncthreads();
    if (t < 32) {
      int lg = base + g0 + t;
      *(int4*)&yb[(size_t)lg * DI + d0] = *(const int4*)&syt[t][0];
    }
  }
}

// ---------------- launch ----------------
extern "C" void kernel_launch(void* const* d_in, const int* in_sizes, int n_in,
                              void* d_out, int out_size, void* d_ws, size_t ws_size,
                              hipStream_t stream)
{
  const float* x      = (const float*)d_in[0];
  const float* W_in   = (const float*)d_in[1];
  const float* W_conv = (const float*)d_in[2];
  const float* b_conv = (const float*)d_in[3];
  const float* W_x    = (const float*)d_in[4];
  const float* W_dt   = (const float*)d_in[5];
  const float* b_dt   = (const float*)d_in[6];
  const float* A_log  = (const float*)d_in[7];
  const float* Dp     = (const float*)d_in[8];
  const float* W_out  = (const float*)d_in[9];
  const float* ln_s   = (const float*)d_in[10];
  const float* ln_b   = (const float*)d_in[11];

  char* ws = (char*)d_ws;
  const size_t MB = 1u << 20;
  unsigned short* xnb    = (unsigned short*)(ws);               // 0-4
  unsigned short* xrT    = (unsigned short*)(ws + 4 * MB);      // 4-20: bf16 [4096][2048]
  unsigned short* u2T    = (unsigned short*)(ws + 20 * MB);     // 20-28
  unsigned short* u2b    = (unsigned short*)(ws + 28 * MB);     // 28-36 (dead after xdbl gemm)
  float*          hend   = (float*)(ws + 28 * MB);              // 4 MB, aliases u2b
  float*          aprod  = (float*)(ws + 32 * MB);              // 4 MB, aliases u2b
  unsigned short* xdbl   = (unsigned short*)(ws + 36 * MB);     // 0.5 MB
  unsigned short* Wxt    = (unsigned short*)(ws + 36 * MB + 512 * 1024); // 0.5 MB
  unsigned short* Wdt_t  = (unsigned short*)(ws + 37 * MB);     // 0.25 MB
  unsigned short* deltaTb= (unsigned short*)(ws + 38 * MB);     // 38-46: bf16 [2048][2048]
  unsigned short* Wtin   = (unsigned short*)(ws + 38 * MB);     // aliases deltaTb (dead before delta GEMM)
  float*          part   = (float*)(ws + 46 * MB);              // 46-54: xdbl split-K partials (8 MB)
  float*          h_in   = (float*)(ws + 62 * MB);              // 62-66
  unsigned short* Wtout  = (unsigned short*)(ws + 66 * MB);     // 66-70
  unsigned short* yb     = (unsigned short*)(ws + 4 * MB);      // aliases dead u-rows of xrT
  const unsigned short* resT = xrT + (size_t)DI * L_SEQ;        // rows [2048,4096)

  prep_all<<<3632, 256, 0, stream>>>(x, ln_s, ln_b, xnb,
                                     W_in, W_out, W_dt, W_x,
                                     Wtin, Wtout, Wdt_t, Wxt);

  gemm2<128, 128, 0, 1, 1><<<dim3(L_SEQ / 128, (2 * DI) / 128), 256, 0, stream>>>(
      Wtin, DM, xnb, DM, xrT, L_SEQ, 2 * DI, L_SEQ, DM, nullptr, nullptr, 0);

  conv_silu_fused<<<dim3(DI / 64, L_SEQ / 128), 256, 0, stream>>>(
      xrT, W_conv, b_conv, u2T, u2b);

  gemm2<64, 128, 0, 0, 8><<<dim3(1, L_SEQ / 64, 8), 256, 0, stream>>>(
      u2b, DI, Wxt, DI, part, 128, L_SEQ, 128, DI, nullptr, nullptr, 0);

  xdbl_reduce<<<(L_SEQ * 128) / 1024, 256, 0, stream>>>(part, xdbl);

  gemm2<64, 128, 1, 1, 1><<<dim3(L_SEQ / 128, DI / 64), 256, 0, stream>>>(
      Wdt_t, DTR, xdbl, 128, deltaTb, L_SEQ, DI, L_SEQ, DTR, b_dt, nullptr, 0);

  scan_pass1<<<dim3(DI / 8, NSEG - 1), 128, 0, stream>>>(
      deltaTb, u2T, xdbl, A_log, hend, aprod);

  scan_pass2<<<NSTATE / 256, 256, 0, stream>>>(hend, aprod, h_in);

  scan_pass3<<<dim3(DI / 8, NSEG), 128, 0, stream>>>(
      deltaTb, u2T, resT, xdbl, A_log, Dp, h_in, yb);

  // final: out = y @ W_out + x, split-K=1, fused residual epilogue
  gemm2<64, 64, 2, 0, 1><<<dim3(DM / 64, L_SEQ / 64), 256, 0, stream>>>(
      yb, DI, Wtout, DI, (float*)d_out, DM, L_SEQ, DM, DI, nullptr, x, DM);
}

// Round 13
// 166.139 us; speedup vs baseline: 1.0859x; 1.0859x over previous
//
#include <hip/hip_runtime.h>
#include <math.h>

#define L_SEQ 2048
#define DM 1024
#define DI 2048
#define DS 16
#define DTR 64
#define EPS 1e-5f
#define NSEG 32
#define SEGLEN 64
#define NSTATE (DI * DS)

typedef float f32x4 __attribute__((ext_vector_type(4)));
typedef __bf16 bf16x8 __attribute__((ext_vector_type(8)));
typedef _Float16 h16x2 __attribute__((ext_vector_type(2)));

static __device__ __forceinline__ unsigned short f2bf(float f) {
  union { float f; unsigned u; } v; v.f = f;
  unsigned r = v.u + 0x7fffu + ((v.u >> 16) & 1u);
  return (unsigned short)(r >> 16);
}
static __device__ __forceinline__ float bf2f(unsigned short s) {
  union { unsigned u; float f; } v; v.u = ((unsigned)s) << 16;
  return v.f;
}

// global -> LDS direct copy, 16B per lane (wave-uniform LDS base).
static __device__ __forceinline__ void gload16(const void* g, void* l) {
  __builtin_amdgcn_global_load_lds(
      (__attribute__((address_space(1))) void*)(unsigned long long)(g),
      (__attribute__((address_space(3))) void*)(unsigned)(unsigned long long)(l),
      16, 0, 0);
}

// ---------------- shared transpose tile: W[K][N] fp32 -> Wt[N][K] bf16 ----------------
static __device__ __forceinline__ void trans_tile(
    const float* __restrict__ W, unsigned short* __restrict__ Wt,
    int K, int N, int n0, int k0)
{
  __shared__ unsigned short s[64][80];
  int tid = threadIdx.x;
  #pragma unroll
  for (int p = 0; p < 4; ++p) {
    int i = p * 16 + (tid >> 4);
    int j = (tid & 15) * 4;
    float4 w = *(const float4*)&W[(size_t)(k0 + i) * N + n0 + j];
    s[j + 0][i] = f2bf(w.x); s[j + 1][i] = f2bf(w.y);
    s[j + 2][i] = f2bf(w.z); s[j + 3][i] = f2bf(w.w);
  }
  __syncthreads();
  #pragma unroll
  for (int q = 0; q < 2; ++q) {
    int n = q * 32 + (tid >> 3);
    int i8 = (tid & 7) * 8;
    *(int4*)&Wt[(size_t)(n0 + n) * K + k0 + i8] = *(const int4*)&s[n][i8];
  }
}

// ---------------- merged prep: LN + Wtin + Wtout + Wdt_t + Wxt in ONE launch ----------------
__global__ __launch_bounds__(256) void prep_all(
    const float* __restrict__ x, const float* __restrict__ ln_s,
    const float* __restrict__ ln_b, unsigned short* __restrict__ xnb,
    const float* __restrict__ W_in, const float* __restrict__ W_out,
    const float* __restrict__ W_dt, const float* __restrict__ Wx,
    unsigned short* __restrict__ Wtin, unsigned short* __restrict__ Wtout,
    unsigned short* __restrict__ Wdt_t, unsigned short* __restrict__ Wxt)
{
  int b = blockIdx.x;
  int t = threadIdx.x;
  if (b < 2048) {
    __shared__ float red[8];
    int row = b;
    float4 xv = ((const float4*)(x + (size_t)row * DM))[t];
    float s  = xv.x + xv.y + xv.z + xv.w;
    float s2 = xv.x*xv.x + xv.y*xv.y + xv.z*xv.z + xv.w*xv.w;
    #pragma unroll
    for (int m = 32; m >= 1; m >>= 1) {
      s  += __shfl_xor(s, m);
      s2 += __shfl_xor(s2, m);
    }
    int wid = t >> 6, lane = t & 63;
    if (lane == 0) { red[wid] = s; red[4 + wid] = s2; }
    __syncthreads();
    s  = red[0] + red[1] + red[2] + red[3];
    s2 = red[4] + red[5] + red[6] + red[7];
    float mu = s * (1.f / DM);
    float var = s2 * (1.f / DM) - mu * mu;
    float rs = rsqrtf(var + EPS);
    float4 sc4 = ((const float4*)ln_s)[t];
    float4 bi4 = ((const float4*)ln_b)[t];
    ushort4 ob;
    ob.x = f2bf((xv.x - mu) * rs * sc4.x + bi4.x);
    ob.y = f2bf((xv.y - mu) * rs * sc4.y + bi4.y);
    ob.z = f2bf((xv.z - mu) * rs * sc4.z + bi4.z);
    ob.w = f2bf((xv.w - mu) * rs * sc4.w + bi4.w);
    *(ushort4*)&xnb[(size_t)row * DM + t * 4] = ob;
  } else if (b < 3072) {
    int r = b - 2048;
    trans_tile(W_in, Wtin, DM, 2 * DI, (r & 63) * 64, (r >> 6) * 64);
  } else if (b < 3584) {
    int r = b - 3072;
    trans_tile(W_out, Wtout, DI, DM, (r & 15) * 64, (r >> 4) * 64);
  } else if (b < 3616) {
    int r = b - 3584;
    trans_tile(W_dt, Wdt_t, DTR, DI, r * 64, 0);
  } else {
    int r = b - 3616;
    int i = r * 256 + t;
    #pragma unroll
    for (int p = 0; p < 64; ++p) {
      int ii = i + p * 4096;
      int n = ii >> 11, k = ii & 2047;
      Wxt[ii] = (n < 96) ? f2bf(Wx[(size_t)k * 96 + n]) : (unsigned short)0;
    }
  }
}

// ---------------- bf16 MFMA GEMM v3: optional 2-phase prefetch pipeline ----------------
// PIPE=1: double-buffered LDS; STAGE(kt+1) issued BEFORE COMPUTE(kt) so
// global_load_lds flies under ds_read+MFMA; ONE barrier per K-iter (its
// implicit vmcnt(0) waits a now-short remainder). Overwrite of buf^1 is safe:
// previous iteration's barrier means all waves finished reading it.
// EPI: 0 none, 1 softplus(acc+bias[row]), 2 acc + R[row][col] (fp32 out only)
template<int BM, int BN, int EPI, int OUTB, int SPLITK, int PIPE>
__global__ __launch_bounds__(256) void gemm2(
    const unsigned short* __restrict__ A, int lda,
    const unsigned short* __restrict__ Bt, int ldb,
    void* __restrict__ Cv, int ldc,
    int M, int N, int K,
    const float* __restrict__ bias,
    const float* __restrict__ R, int ldr)
{
  constexpr int WM = BM / 2, WN = BN / 2;
  constexpr int FM = WM / 16, FN = WN / 16;
  constexpr int BUFE = (BM + BN) * 64;
  __shared__ __align__(16) unsigned short sm[BUFE * (PIPE ? 2 : 1)];

  int nwg = gridDim.x * gridDim.y;
  int bid = blockIdx.y * gridDim.x + blockIdx.x;
  if ((nwg & 7) == 0) {
    int cpx = nwg >> 3;
    bid = (bid & 7) * cpx + (bid >> 3);
  }
  int bx = bid % gridDim.x;
  int by = bid / gridDim.x;
  int m0 = by * BM, n0 = bx * BN;

  int tid = threadIdx.x;
  int lane = tid & 63, wid = tid >> 6;
  int wm = wid >> 1, wn = wid & 1;

  int kb = blockIdx.z * (K / SPLITK);
  int nt = (K / SPLITK) / 64;

  int rs = lane >> 3;
  int cs = (lane & 7) * 8;

  f32x4 acc[FM][FN];
  #pragma unroll
  for (int m = 0; m < FM; ++m)
    #pragma unroll
    for (int n = 0; n < FN; ++n) acc[m][n] = (f32x4){0.f, 0.f, 0.f, 0.f};

  auto STAGE = [&](int kt, int buf) {
    unsigned short* bA = sm + buf * BUFE;
    unsigned short* bB = bA + BM * 64;
    #pragma unroll
    for (int i = 0; i < BM / 32; ++i) {
      int chunk = wid * (BM / 32) + i;
      gload16(A + (size_t)(m0 + chunk * 8 + rs) * lda + kb + kt * 64 + cs,
              (char*)bA + chunk * 1024);
    }
    #pragma unroll
    for (int i = 0; i < BN / 32; ++i) {
      int chunk = wid * (BN / 32) + i;
      gload16(Bt + (size_t)(n0 + chunk * 8 + rs) * ldb + kb + kt * 64 + cs,
              (char*)bB + chunk * 1024);
    }
  };

  auto COMPUTE = [&](const unsigned short* bA, const unsigned short* bB) {
    #pragma unroll
    for (int kk = 0; kk < 2; ++kk) {
      bf16x8 aF[FM], bF[FN];
      #pragma unroll
      for (int m = 0; m < FM; ++m) {
        int r = wm * WM + m * 16 + (lane & 15);
        aF[m] = *(const bf16x8*)((const char*)bA + r * 128 + kk * 64 + (lane >> 4) * 16);
      }
      #pragma unroll
      for (int n = 0; n < FN; ++n) {
        int r = wn * WN + n * 16 + (lane & 15);
        bF[n] = *(const bf16x8*)((const char*)bB + r * 128 + kk * 64 + (lane >> 4) * 16);
      }
      #pragma unroll
      for (int m = 0; m < FM; ++m)
        #pragma unroll
        for (int n = 0; n < FN; ++n)
          acc[m][n] = __builtin_amdgcn_mfma_f32_16x16x32_bf16(
              aF[m], bF[n], acc[m][n], 0, 0, 0);
    }
  };

  if (PIPE) {
    STAGE(0, 0);
    __syncthreads();          // drains prologue loads
    int cur = 0;
    for (int kt = 0; kt < nt; ++kt) {
      if (kt + 1 < nt) STAGE(kt + 1, cur ^ 1);   // loads fly under compute
      COMPUTE(sm + cur * BUFE, sm + cur * BUFE + BM * 64);
      __syncthreads();        // implicit vmcnt(0): short wait, loads mostly landed
      cur ^= 1;
    }
  } else {
    for (int kt = 0; kt < nt; ++kt) {
      __syncthreads();
      STAGE(kt, 0);
      __syncthreads();
      COMPUTE(sm, sm + BM * 64);
    }
    __syncthreads();
  }

  int cm = (lane >> 4) * 4, cn = lane & 15;
  if (OUTB) {
    unsigned short* Cb = (unsigned short*)Cv;
    __syncthreads();
    #pragma unroll
    for (int m = 0; m < FM; ++m)
      #pragma unroll
      for (int n = 0; n < FN; ++n) {
        int col = wn * WN + n * 16 + cn;
        #pragma unroll
        for (int r = 0; r < 4; ++r) {
          int row = wm * WM + m * 16 + cm + r;
          float v = acc[m][n][r];
          if (EPI == 1) {
            float w = v + bias[m0 + row];
            v = (w > 20.f) ? w : log1pf(__expf(w));
          }
          sm[row * BN + col] = f2bf(v);
        }
      }
    __syncthreads();
    constexpr int NI4 = BM * BN / 8;
    for (int k = tid; k < NI4; k += 256) {
      int row = k / (BN / 8);
      int c8 = (k % (BN / 8)) * 8;
      *(int4*)&Cb[(size_t)(m0 + row) * ldc + n0 + c8] = *(const int4*)&sm[row * BN + c8];
    }
  } else {
    float* Cf = (float*)Cv + (size_t)blockIdx.z * M * ldc;
    #pragma unroll
    for (int m = 0; m < FM; ++m)
      #pragma unroll
      for (int n = 0; n < FN; ++n) {
        int col = n0 + wn * WN + n * 16 + cn;
        #pragma unroll
        for (int r = 0; r < 4; ++r) {
          int row = m0 + wm * WM + m * 16 + cm + r;
          float v = acc[m][n][r];
          if (EPI == 1) {
            float w = v + bias[row];
            v = (w > 20.f) ? w : log1pf(__expf(w));
          }
          if (EPI == 2) v += R[(size_t)row * ldr + col];
          Cf[(size_t)row * ldc + col] = v;
        }
      }
  }
}

// ---------------- split-K reduce: part[8][2048*128] fp32 -> xdbl bf16 ----------------
__global__ __launch_bounds__(256) void xdbl_reduce(
    const float* __restrict__ part, unsigned short* __restrict__ xdbl)
{
  int i = (blockIdx.x * 256 + threadIdx.x) * 4;
  const int SL = 2048 * 128;
  float4 s = *(const float4*)&part[i];
  #pragma unroll
  for (int z = 1; z < 8; ++z) {
    float4 p = *(const float4*)&part[(size_t)z * SL + i];
    s.x += p.x; s.y += p.y; s.z += p.z; s.w += p.w;
  }
  ushort4 ob;
  ob.x = f2bf(s.x); ob.y = f2bf(s.y); ob.z = f2bf(s.z); ob.w = f2bf(s.w);
  *(ushort4*)&xdbl[i] = ob;
}

// ---------------- causal conv4 + SiLU, dual-layout output ----------------
__global__ __launch_bounds__(256) void conv_silu_fused(
    const unsigned short* __restrict__ xrT,
    const float* __restrict__ Wc, const float* __restrict__ bc,
    unsigned short* __restrict__ u2T, unsigned short* __restrict__ u2b)
{
  __shared__ unsigned short st[128][68];   // [l][d] tile
  int d0 = blockIdx.x * 64, l0 = blockIdx.y * 128;
  int tid = threadIdx.x;
  int dloc = tid & 63;
  int lp = (tid >> 6) * 32;
  int d = d0 + dloc;
  const unsigned short* ur = xrT + (size_t)d * L_SEQ + l0 + lp;
  float w0 = Wc[0 * DI + d], w1 = Wc[1 * DI + d];
  float w2 = Wc[2 * DI + d], w3 = Wc[3 * DI + d];
  float b = bc[d];

  ushort4 vin[8];
  #pragma unroll
  for (int j = 0; j < 8; ++j) vin[j] = *(const ushort4*)&ur[j * 4];
  ushort4 vh; vh.x = vh.y = vh.z = vh.w = 0;
  if (l0 + lp > 0) vh = *(const ushort4*)&ur[-4];
  float prev3 = bf2f(vh.y), prev2 = bf2f(vh.z), prev1 = bf2f(vh.w);

  #pragma unroll
  for (int j = 0; j < 8; ++j) {
    float xs[4] = {bf2f(vin[j].x), bf2f(vin[j].y), bf2f(vin[j].z), bf2f(vin[j].w)};
    ushort4 ob;
    unsigned short* o = (unsigned short*)&ob;
    #pragma unroll
    for (int i = 0; i < 4; ++i) {
      float y = b + w0 * prev3 + w1 * prev2 + w2 * prev1 + w3 * xs[i];
      prev3 = prev2; prev2 = prev1; prev1 = xs[i];
      float sig = 1.f / (1.f + __expf(-y));
      o[i] = f2bf(y * sig);
    }
    *(ushort4*)&u2T[(size_t)d * L_SEQ + l0 + lp + j * 4] = ob;
    st[lp + j * 4 + 0][dloc] = o[0];
    st[lp + j * 4 + 1][dloc] = o[1];
    st[lp + j * 4 + 2][dloc] = o[2];
    st[lp + j * 4 + 3][dloc] = o[3];
  }
  __syncthreads();
  int lr = tid >> 1, hf = (tid & 1) * 32;
  unsigned short* ob = &u2b[(size_t)(l0 + lr) * DI + d0 + hf];
  *(int4*)&ob[0]  = *(const int4*)&st[lr][hf + 0];
  *(int4*)&ob[8]  = *(const int4*)&st[lr][hf + 8];
  *(int4*)&ob[16] = *(const int4*)&st[lr][hf + 16];
  *(int4*)&ob[24] = *(const int4*)&st[lr][hf + 24];
}

// ================= segmented selective scan =================

__global__ __launch_bounds__(128) void scan_pass1(
    const unsigned short* __restrict__ deltaT, const unsigned short* __restrict__ u2T,
    const unsigned short* __restrict__ xdbl,
    const float* __restrict__ A_log,
    float* __restrict__ hend, float* __restrict__ aprod)
{
  int t = threadIdx.x;
  int ch = t >> 4, n = t & 15;
  int li = (t & 15) * 4;
  int d0 = blockIdx.x * 8, d = d0 + ch;
  int base = blockIdx.y * SEGLEN;

  __shared__ __align__(16) float sdT[8][68], suT[8][68], sBT[16][68];

  float An = -__expf(A_log[d * DS + n]);

  ushort4 rdu = *(const ushort4*)&deltaT[(size_t)d * L_SEQ + base + li];
  ushort4 ru  = *(const ushort4*)&u2T[(size_t)d * L_SEQ + base + li];
  ushort4 rB[2];
  #pragma unroll
  for (int q = 0; q < 2; ++q) {
    int ll = base + (t >> 2) + q * 32;
    rB[q] = *(const ushort4*)&xdbl[(size_t)ll * 128 + 64 + (t & 3) * 4];
  }

  float d0v = bf2f(rdu.x), d1v = bf2f(rdu.y), d2v = bf2f(rdu.z), d3v = bf2f(rdu.w);
  sdT[ch][li + 0] = d0v; sdT[ch][li + 1] = d1v;
  sdT[ch][li + 2] = d2v; sdT[ch][li + 3] = d3v;
  suT[ch][li + 0] = d0v * bf2f(ru.x); suT[ch][li + 1] = d1v * bf2f(ru.y);
  suT[ch][li + 2] = d2v * bf2f(ru.z); suT[ch][li + 3] = d3v * bf2f(ru.w);
  #pragma unroll
  for (int q = 0; q < 2; ++q) {
    int ll = (t >> 2) + q * 32;
    int nb = (t & 3) * 4;
    sBT[nb + 0][ll] = bf2f(rB[q].x); sBT[nb + 1][ll] = bf2f(rB[q].y);
    sBT[nb + 2][ll] = bf2f(rB[q].z); sBT[nb + 3][ll] = bf2f(rB[q].w);
  }
  __syncthreads();

  float h = 0.f, sdl = 0.f;
  #pragma unroll
  for (int g = 0; g < 64; g += 4) {
    float4 dl4 = *(const float4*)&sdT[ch][g];
    float4 du4 = *(const float4*)&suT[ch][g];
    float4 Bn4 = *(const float4*)&sBT[n][g];
    float dl[4] = {dl4.x, dl4.y, dl4.z, dl4.w};
    float du[4] = {du4.x, du4.y, du4.z, du4.w};
    float Bn[4] = {Bn4.x, Bn4.y, Bn4.z, Bn4.w};
    #pragma unroll
    for (int i = 0; i < 4; ++i) {
      float dA = __expf(dl[i] * An);
      sdl += dl[i];
      h = dA * h + du[i] * Bn[i];
    }
  }
  size_t idx = (size_t)blockIdx.y * NSTATE + d0 * DS + t;
  hend[idx]  = h;
  aprod[idx] = __expf(An * sdl);   // prod of exp == exp of sum
}

// ---- pass 2: prefix over segment summaries -> h_in ----
__global__ __launch_bounds__(256) void scan_pass2(
    const float* __restrict__ hend, const float* __restrict__ aprod,
    float* __restrict__ h_in)
{
  int i = blockIdx.x * 256 + threadIdx.x;
  float h = 0.f;
  h_in[i] = 0.f;
  for (int s = 0; s < NSEG - 1; ++s) {
    h = aprod[(size_t)s * NSTATE + i] * h + hend[(size_t)s * NSTATE + i];
    h_in[(size_t)(s + 1) * NSTATE + i] = h;
  }
}

// ---- pass 3: full scan per segment; writes yb [l][di] directly ----
__global__ __launch_bounds__(128) void scan_pass3(
    const unsigned short* __restrict__ deltaT, const unsigned short* __restrict__ u2T,
    const unsigned short* __restrict__ resT,
    const unsigned short* __restrict__ xdbl,
    const float* __restrict__ A_log, const float* __restrict__ Dp,
    const float* __restrict__ h_in,
    unsigned short* __restrict__ yb)
{
  int t = threadIdx.x;
  int ch = t >> 4, n = t & 15;
  int li = (t & 15) * 4;
  int d0 = blockIdx.x * 8, d = d0 + ch;
  int s = blockIdx.y;
  int base = s * SEGLEN;

  __shared__ __align__(16) float sdT[8][68], suT[8][68];
  __shared__ __align__(16) float sBT[16][68], sCT[16][68];
  __shared__ __align__(4) _Float16 svh[32][134];
  __shared__ __align__(16) unsigned short syt[32][8];

  float An = -__expf(A_log[d * DS + n]);
  float h = h_in[(size_t)s * NSTATE + d0 * DS + t];

  ushort4 rdu = *(const ushort4*)&deltaT[(size_t)d * L_SEQ + base + li];
  ushort4 ru  = *(const ushort4*)&u2T[(size_t)d * L_SEQ + base + li];
  ushort4 rB[2], rC[2];
  #pragma unroll
  for (int q = 0; q < 2; ++q) {
    int ll = base + (t >> 2) + q * 32;
    int n4 = (t & 3) * 4;
    rB[q] = *(const ushort4*)&xdbl[(size_t)ll * 128 + 64 + n4];
    rC[q] = *(const ushort4*)&xdbl[(size_t)ll * 128 + 80 + n4];
  }

  float d0v = bf2f(rdu.x), d1v = bf2f(rdu.y), d2v = bf2f(rdu.z), d3v = bf2f(rdu.w);
  sdT[ch][li + 0] = d0v; sdT[ch][li + 1] = d1v;
  sdT[ch][li + 2] = d2v; sdT[ch][li + 3] = d3v;
  suT[ch][li + 0] = d0v * bf2f(ru.x); suT[ch][li + 1] = d1v * bf2f(ru.y);
  suT[ch][li + 2] = d2v * bf2f(ru.z); suT[ch][li + 3] = d3v * bf2f(ru.w);
  #pragma unroll
  for (int q = 0; q < 2; ++q) {
    int ll = (t >> 2) + q * 32;
    int nb = (t & 3) * 4;
    sBT[nb + 0][ll] = bf2f(rB[q].x); sBT[nb + 1][ll] = bf2f(rB[q].y);
    sBT[nb + 2][ll] = bf2f(rB[q].z); sBT[nb + 3][ll] = bf2f(rB[q].w);
    sCT[nb + 0][ll] = bf2f(rC[q].x); sCT[nb + 1][ll] = bf2f(rC[q].y);
    sCT[nb + 2][ll] = bf2f(rC[q].z); sCT[nb + 3][ll] = bf2f(rC[q].w);
  }
  __syncthreads();

  #pragma unroll
  for (int half = 0; half < 2; ++half) {
    int g0 = half * 32;
    #pragma unroll
    for (int g = g0; g < g0 + 32; g += 4) {
      float4 dl4 = *(const float4*)&sdT[ch][g];
      float4 du4 = *(const float4*)&suT[ch][g];
      float4 Bn4 = *(const float4*)&sBT[n][g];
      float4 Cn4 = *(const float4*)&sCT[n][g];
      float dl[4] = {dl4.x, dl4.y, dl4.z, dl4.w};
      float du[4] = {du4.x, du4.y, du4.z, du4.w};
      float Bn[4] = {Bn4.x, Bn4.y, Bn4.z, Bn4.w};
      float Cn[4] = {Cn4.x, Cn4.y, Cn4.z, Cn4.w};
      #pragma unroll
      for (int i = 0; i < 4; ++i) {
        float dA = __expf(dl[i] * An);
        h = dA * h + du[i] * Bn[i];
        svh[g - g0 + i][t] = (_Float16)(h * Cn[i]);
      }
    }
    __syncthreads();

    #pragma unroll
    for (int r = 0; r < 2; ++r) {
      int idx = r * 128 + t;
      int ll = idx & 31, c2 = idx >> 5;
      const _Float16* row = &svh[ll][c2 * 16];
      float sum = 0.f;
      #pragma unroll
      for (int k = 0; k < 8; ++k) {
        h16x2 pv = *(const h16x2*)&row[k * 2];
        sum += (float)pv.x + (float)pv.y;
      }
      int dd = d0 + c2;
      int lg = base + g0 + ll;
      float uv = bf2f(u2T[(size_t)dd * L_SEQ + lg]);
      float rv = bf2f(resT[(size_t)dd * L_SEQ + lg]);
      float sig = 1.f / (1.f + __expf(-rv));
      syt[ll][c2] = f2bf((sum + uv * Dp[dd]) * rv * sig);
    }
    __syncthreads();
    if (t < 32) {
      int lg = base + g0 + t;
      *(int4*)&yb[(size_t)lg * DI + d0] = *(const int4*)&syt[t][0];
    }
  }
}

// ---------------- launch ----------------
extern "C" void kernel_launch(void* const* d_in, const int* in_sizes, int n_in,
                              void* d_out, int out_size, void* d_ws, size_t ws_size,
                              hipStream_t stream)
{
  const float* x      = (const float*)d_in[0];
  const float* W_in   = (const float*)d_in[1];
  const float* W_conv = (const float*)d_in[2];
  const float* b_conv = (const float*)d_in[3];
  const float* W_x    = (const float*)d_in[4];
  const float* W_dt   = (const float*)d_in[5];
  const float* b_dt   = (const float*)d_in[6];
  const float* A_log  = (const float*)d_in[7];
  const float* Dp     = (const float*)d_in[8];
  const float* W_out  = (const float*)d_in[9];
  const float* ln_s   = (const float*)d_in[10];
  const float* ln_b   = (const float*)d_in[11];

  char* ws = (char*)d_ws;
  const size_t MB = 1u << 20;
  unsigned short* xnb    = (unsigned short*)(ws);               // 0-4
  unsigned short* xrT    = (unsigned short*)(ws + 4 * MB);      // 4-20: bf16 [4096][2048]
  unsigned short* u2T    = (unsigned short*)(ws + 20 * MB);     // 20-28
  unsigned short* u2b    = (unsigned short*)(ws + 28 * MB);     // 28-36 (dead after xdbl gemm)
  float*          hend   = (float*)(ws + 28 * MB);              // 4 MB, aliases u2b
  float*          aprod  = (float*)(ws + 32 * MB);              // 4 MB, aliases u2b
  unsigned short* xdbl   = (unsigned short*)(ws + 36 * MB);     // 0.5 MB
  unsigned short* Wxt    = (unsigned short*)(ws + 36 * MB + 512 * 1024); // 0.5 MB
  unsigned short* Wdt_t  = (unsigned short*)(ws + 37 * MB);     // 0.25 MB
  unsigned short* deltaTb= (unsigned short*)(ws + 38 * MB);     // 38-46: bf16 [2048][2048]
  unsigned short* Wtin   = (unsigned short*)(ws + 38 * MB);     // aliases deltaTb (dead before delta GEMM)
  float*          part   = (float*)(ws + 46 * MB);              // 46-54: xdbl split-K partials (8 MB)
  float*          h_in   = (float*)(ws + 62 * MB);              // 62-66
  unsigned short* Wtout  = (unsigned short*)(ws + 66 * MB);     // 66-70
  unsigned short* yb     = (unsigned short*)(ws + 4 * MB);      // aliases dead u-rows of xrT
  const unsigned short* resT = xrT + (size_t)DI * L_SEQ;        // rows [2048,4096)

  prep_all<<<3632, 256, 0, stream>>>(x, ln_s, ln_b, xnb,
                                     W_in, W_out, W_dt, W_x,
                                     Wtin, Wtout, Wdt_t, Wxt);

  gemm2<128, 128, 0, 1, 1, 1><<<dim3(L_SEQ / 128, (2 * DI) / 128), 256, 0, stream>>>(
      Wtin, DM, xnb, DM, xrT, L_SEQ, 2 * DI, L_SEQ, DM, nullptr, nullptr, 0);

  conv_silu_fused<<<dim3(DI / 64, L_SEQ / 128), 256, 0, stream>>>(
      xrT, W_conv, b_conv, u2T, u2b);

  gemm2<64, 128, 0, 0, 8, 1><<<dim3(1, L_SEQ / 64, 8), 256, 0, stream>>>(
      u2b, DI, Wxt, DI, part, 128, L_SEQ, 128, DI, nullptr, nullptr, 0);

  xdbl_reduce<<<(L_SEQ * 128) / 1024, 256, 0, stream>>>(part, xdbl);

  gemm2<64, 128, 1, 1, 1, 0><<<dim3(L_SEQ / 128, DI / 64), 256, 0, stream>>>(
      Wdt_t, DTR, xdbl, 128, deltaTb, L_SEQ, DI, L_SEQ, DTR, b_dt, nullptr, 0);

  scan_pass1<<<dim3(DI / 8, NSEG - 1), 128, 0, stream>>>(
      deltaTb, u2T, xdbl, A_log, hend, aprod);

  scan_pass2<<<NSTATE / 256, 256, 0, stream>>>(hend, aprod, h_in);

  scan_pass3<<<dim3(DI / 8, NSEG), 128, 0, stream>>>(
      deltaTb, u2T, resT, xdbl, A_log, Dp, h_in, yb);

  // final: out = y @ W_out + x, split-K=1, fused residual epilogue, deep pipeline
  gemm2<64, 64, 2, 0, 1, 1><<<dim3(DM / 64, L_SEQ / 64), 256, 0, stream>>>(
      yb, DI, Wtout, DI, (float*)d_out, DM, L_SEQ, DM, DI, nullptr, x, DM);
}

// Round 14
// 163.726 us; speedup vs baseline: 1.1019x; 1.0147x over previous
//
#include <hip/hip_runtime.h>
#include <math.h>

#define L_SEQ 2048
#define DM 1024
#define DI 2048
#define DS 16
#define DTR 64
#define EPS 1e-5f
#define NSEG 32
#define SEGLEN 64
#define NSTATE (DI * DS)

typedef float f32x4 __attribute__((ext_vector_type(4)));
typedef __bf16 bf16x8 __attribute__((ext_vector_type(8)));
typedef _Float16 h16x2 __attribute__((ext_vector_type(2)));

static __device__ __forceinline__ unsigned short f2bf(float f) {
  union { float f; unsigned u; } v; v.f = f;
  unsigned r = v.u + 0x7fffu + ((v.u >> 16) & 1u);
  return (unsigned short)(r >> 16);
}
static __device__ __forceinline__ float bf2f(unsigned short s) {
  union { unsigned u; float f; } v; v.u = ((unsigned)s) << 16;
  return v.f;
}

// global -> LDS direct copy, 16B per lane (wave-uniform LDS base).
static __device__ __forceinline__ void gload16(const void* g, void* l) {
  __builtin_amdgcn_global_load_lds(
      (__attribute__((address_space(1))) void*)(unsigned long long)(g),
      (__attribute__((address_space(3))) void*)(unsigned)(unsigned long long)(l),
      16, 0, 0);
}

// ---------------- shared transpose tile: W[K][N] fp32 -> Wt[N][K] bf16 ----------------
static __device__ __forceinline__ void trans_tile(
    const float* __restrict__ W, unsigned short* __restrict__ Wt,
    int K, int N, int n0, int k0)
{
  __shared__ unsigned short s[64][80];
  int tid = threadIdx.x;
  #pragma unroll
  for (int p = 0; p < 4; ++p) {
    int i = p * 16 + (tid >> 4);
    int j = (tid & 15) * 4;
    float4 w = *(const float4*)&W[(size_t)(k0 + i) * N + n0 + j];
    s[j + 0][i] = f2bf(w.x); s[j + 1][i] = f2bf(w.y);
    s[j + 2][i] = f2bf(w.z); s[j + 3][i] = f2bf(w.w);
  }
  __syncthreads();
  #pragma unroll
  for (int q = 0; q < 2; ++q) {
    int n = q * 32 + (tid >> 3);
    int i8 = (tid & 7) * 8;
    *(int4*)&Wt[(size_t)(n0 + n) * K + k0 + i8] = *(const int4*)&s[n][i8];
  }
}

// ---------------- merged prep: LN + Wtin + Wtout + Wdt_t + Wxt in ONE launch ----------------
__global__ __launch_bounds__(256) void prep_all(
    const float* __restrict__ x, const float* __restrict__ ln_s,
    const float* __restrict__ ln_b, unsigned short* __restrict__ xnb,
    const float* __restrict__ W_in, const float* __restrict__ W_out,
    const float* __restrict__ W_dt, const float* __restrict__ Wx,
    unsigned short* __restrict__ Wtin, unsigned short* __restrict__ Wtout,
    unsigned short* __restrict__ Wdt_t, unsigned short* __restrict__ Wxt)
{
  int b = blockIdx.x;
  int t = threadIdx.x;
  if (b < 2048) {
    __shared__ float red[8];
    int row = b;
    float4 xv = ((const float4*)(x + (size_t)row * DM))[t];
    float s  = xv.x + xv.y + xv.z + xv.w;
    float s2 = xv.x*xv.x + xv.y*xv.y + xv.z*xv.z + xv.w*xv.w;
    #pragma unroll
    for (int m = 32; m >= 1; m >>= 1) {
      s  += __shfl_xor(s, m);
      s2 += __shfl_xor(s2, m);
    }
    int wid = t >> 6, lane = t & 63;
    if (lane == 0) { red[wid] = s; red[4 + wid] = s2; }
    __syncthreads();
    s  = red[0] + red[1] + red[2] + red[3];
    s2 = red[4] + red[5] + red[6] + red[7];
    float mu = s * (1.f / DM);
    float var = s2 * (1.f / DM) - mu * mu;
    float rs = rsqrtf(var + EPS);
    float4 sc4 = ((const float4*)ln_s)[t];
    float4 bi4 = ((const float4*)ln_b)[t];
    ushort4 ob;
    ob.x = f2bf((xv.x - mu) * rs * sc4.x + bi4.x);
    ob.y = f2bf((xv.y - mu) * rs * sc4.y + bi4.y);
    ob.z = f2bf((xv.z - mu) * rs * sc4.z + bi4.z);
    ob.w = f2bf((xv.w - mu) * rs * sc4.w + bi4.w);
    *(ushort4*)&xnb[(size_t)row * DM + t * 4] = ob;
  } else if (b < 3072) {
    int r = b - 2048;
    trans_tile(W_in, Wtin, DM, 2 * DI, (r & 63) * 64, (r >> 6) * 64);
  } else if (b < 3584) {
    int r = b - 3072;
    trans_tile(W_out, Wtout, DI, DM, (r & 15) * 64, (r >> 4) * 64);
  } else if (b < 3616) {
    int r = b - 3584;
    trans_tile(W_dt, Wdt_t, DTR, DI, r * 64, 0);
  } else {
    int r = b - 3616;
    int i = r * 256 + t;
    #pragma unroll
    for (int p = 0; p < 64; ++p) {
      int ii = i + p * 4096;
      int n = ii >> 11, k = ii & 2047;
      Wxt[ii] = (n < 96) ? f2bf(Wx[(size_t)k * 96 + n]) : (unsigned short)0;
    }
  }
}

// ---------------- bf16 MFMA GEMM v3: optional 2-phase prefetch pipeline ----------------
template<int BM, int BN, int EPI, int OUTB, int SPLITK, int PIPE>
__global__ __launch_bounds__(256) void gemm2(
    const unsigned short* __restrict__ A, int lda,
    const unsigned short* __restrict__ Bt, int ldb,
    void* __restrict__ Cv, int ldc,
    int M, int N, int K,
    const float* __restrict__ bias,
    const float* __restrict__ R, int ldr)
{
  constexpr int WM = BM / 2, WN = BN / 2;
  constexpr int FM = WM / 16, FN = WN / 16;
  constexpr int BUFE = (BM + BN) * 64;
  __shared__ __align__(16) unsigned short sm[BUFE * (PIPE ? 2 : 1)];

  int nwg = gridDim.x * gridDim.y;
  int bid = blockIdx.y * gridDim.x + blockIdx.x;
  if ((nwg & 7) == 0) {
    int cpx = nwg >> 3;
    bid = (bid & 7) * cpx + (bid >> 3);
  }
  int bx = bid % gridDim.x;
  int by = bid / gridDim.x;
  int m0 = by * BM, n0 = bx * BN;

  int tid = threadIdx.x;
  int lane = tid & 63, wid = tid >> 6;
  int wm = wid >> 1, wn = wid & 1;

  int kb = blockIdx.z * (K / SPLITK);
  int nt = (K / SPLITK) / 64;

  int rs = lane >> 3;
  int cs = (lane & 7) * 8;

  f32x4 acc[FM][FN];
  #pragma unroll
  for (int m = 0; m < FM; ++m)
    #pragma unroll
    for (int n = 0; n < FN; ++n) acc[m][n] = (f32x4){0.f, 0.f, 0.f, 0.f};

  auto STAGE = [&](int kt, int buf) {
    unsigned short* bA = sm + buf * BUFE;
    unsigned short* bB = bA + BM * 64;
    #pragma unroll
    for (int i = 0; i < BM / 32; ++i) {
      int chunk = wid * (BM / 32) + i;
      gload16(A + (size_t)(m0 + chunk * 8 + rs) * lda + kb + kt * 64 + cs,
              (char*)bA + chunk * 1024);
    }
    #pragma unroll
    for (int i = 0; i < BN / 32; ++i) {
      int chunk = wid * (BN / 32) + i;
      gload16(Bt + (size_t)(n0 + chunk * 8 + rs) * ldb + kb + kt * 64 + cs,
              (char*)bB + chunk * 1024);
    }
  };

  auto COMPUTE = [&](const unsigned short* bA, const unsigned short* bB) {
    #pragma unroll
    for (int kk = 0; kk < 2; ++kk) {
      bf16x8 aF[FM], bF[FN];
      #pragma unroll
      for (int m = 0; m < FM; ++m) {
        int r = wm * WM + m * 16 + (lane & 15);
        aF[m] = *(const bf16x8*)((const char*)bA + r * 128 + kk * 64 + (lane >> 4) * 16);
      }
      #pragma unroll
      for (int n = 0; n < FN; ++n) {
        int r = wn * WN + n * 16 + (lane & 15);
        bF[n] = *(const bf16x8*)((const char*)bB + r * 128 + kk * 64 + (lane >> 4) * 16);
      }
      #pragma unroll
      for (int m = 0; m < FM; ++m)
        #pragma unroll
        for (int n = 0; n < FN; ++n)
          acc[m][n] = __builtin_amdgcn_mfma_f32_16x16x32_bf16(
              aF[m], bF[n], acc[m][n], 0, 0, 0);
    }
  };

  if (PIPE) {
    STAGE(0, 0);
    __syncthreads();
    int cur = 0;
    for (int kt = 0; kt < nt; ++kt) {
      if (kt + 1 < nt) STAGE(kt + 1, cur ^ 1);
      COMPUTE(sm + cur * BUFE, sm + cur * BUFE + BM * 64);
      __syncthreads();
      cur ^= 1;
    }
  } else {
    for (int kt = 0; kt < nt; ++kt) {
      __syncthreads();
      STAGE(kt, 0);
      __syncthreads();
      COMPUTE(sm, sm + BM * 64);
    }
    __syncthreads();
  }

  int cm = (lane >> 4) * 4, cn = lane & 15;
  if (OUTB) {
    unsigned short* Cb = (unsigned short*)Cv;
    __syncthreads();
    #pragma unroll
    for (int m = 0; m < FM; ++m)
      #pragma unroll
      for (int n = 0; n < FN; ++n) {
        int col = wn * WN + n * 16 + cn;
        #pragma unroll
        for (int r = 0; r < 4; ++r) {
          int row = wm * WM + m * 16 + cm + r;
          float v = acc[m][n][r];
          if (EPI == 1) {
            float w = v + bias[m0 + row];
            v = (w > 20.f) ? w : log1pf(__expf(w));
          }
          sm[row * BN + col] = f2bf(v);
        }
      }
    __syncthreads();
    constexpr int NI4 = BM * BN / 8;
    for (int k = tid; k < NI4; k += 256) {
      int row = k / (BN / 8);
      int c8 = (k % (BN / 8)) * 8;
      *(int4*)&Cb[(size_t)(m0 + row) * ldc + n0 + c8] = *(const int4*)&sm[row * BN + c8];
    }
  } else {
    float* Cf = (float*)Cv + (size_t)blockIdx.z * M * ldc;
    #pragma unroll
    for (int m = 0; m < FM; ++m)
      #pragma unroll
      for (int n = 0; n < FN; ++n) {
        int col = n0 + wn * WN + n * 16 + cn;
        #pragma unroll
        for (int r = 0; r < 4; ++r) {
          int row = m0 + wm * WM + m * 16 + cm + r;
          float v = acc[m][n][r];
          if (EPI == 1) {
            float w = v + bias[row];
            v = (w > 20.f) ? w : log1pf(__expf(w));
          }
          if (EPI == 2) v += R[(size_t)row * ldr + col];
          Cf[(size_t)row * ldc + col] = v;
        }
      }
  }
}

// ---------------- split-K reduce: part[8][2048*128] fp32 -> xdbl bf16 ----------------
__global__ __launch_bounds__(256) void xdbl_reduce(
    const float* __restrict__ part, unsigned short* __restrict__ xdbl)
{
  int i = (blockIdx.x * 256 + threadIdx.x) * 4;
  const int SL = 2048 * 128;
  float4 s = *(const float4*)&part[i];
  #pragma unroll
  for (int z = 1; z < 8; ++z) {
    float4 p = *(const float4*)&part[(size_t)z * SL + i];
    s.x += p.x; s.y += p.y; s.z += p.z; s.w += p.w;
  }
  ushort4 ob;
  ob.x = f2bf(s.x); ob.y = f2bf(s.y); ob.z = f2bf(s.z); ob.w = f2bf(s.w);
  *(ushort4*)&xdbl[i] = ob;
}

// ---------------- causal conv4 + SiLU, dual-layout output ----------------
__global__ __launch_bounds__(256) void conv_silu_fused(
    const unsigned short* __restrict__ xrT,
    const float* __restrict__ Wc, const float* __restrict__ bc,
    unsigned short* __restrict__ u2T, unsigned short* __restrict__ u2b)
{
  __shared__ unsigned short st[128][68];   // [l][d] tile
  int d0 = blockIdx.x * 64, l0 = blockIdx.y * 128;
  int tid = threadIdx.x;
  int dloc = tid & 63;
  int lp = (tid >> 6) * 32;
  int d = d0 + dloc;
  const unsigned short* ur = xrT + (size_t)d * L_SEQ + l0 + lp;
  float w0 = Wc[0 * DI + d], w1 = Wc[1 * DI + d];
  float w2 = Wc[2 * DI + d], w3 = Wc[3 * DI + d];
  float b = bc[d];

  ushort4 vin[8];
  #pragma unroll
  for (int j = 0; j < 8; ++j) vin[j] = *(const ushort4*)&ur[j * 4];
  ushort4 vh; vh.x = vh.y = vh.z = vh.w = 0;
  if (l0 + lp > 0) vh = *(const ushort4*)&ur[-4];
  float prev3 = bf2f(vh.y), prev2 = bf2f(vh.z), prev1 = bf2f(vh.w);

  #pragma unroll
  for (int j = 0; j < 8; ++j) {
    float xs[4] = {bf2f(vin[j].x), bf2f(vin[j].y), bf2f(vin[j].z), bf2f(vin[j].w)};
    ushort4 ob;
    unsigned short* o = (unsigned short*)&ob;
    #pragma unroll
    for (int i = 0; i < 4; ++i) {
      float y = b + w0 * prev3 + w1 * prev2 + w2 * prev1 + w3 * xs[i];
      prev3 = prev2; prev2 = prev1; prev1 = xs[i];
      float sig = 1.f / (1.f + __expf(-y));
      o[i] = f2bf(y * sig);
    }
    *(ushort4*)&u2T[(size_t)d * L_SEQ + l0 + lp + j * 4] = ob;
    st[lp + j * 4 + 0][dloc] = o[0];
    st[lp + j * 4 + 1][dloc] = o[1];
    st[lp + j * 4 + 2][dloc] = o[2];
    st[lp + j * 4 + 3][dloc] = o[3];
  }
  __syncthreads();
  int lr = tid >> 1, hf = (tid & 1) * 32;
  unsigned short* ob = &u2b[(size_t)(l0 + lr) * DI + d0 + hf];
  *(int4*)&ob[0]  = *(const int4*)&st[lr][hf + 0];
  *(int4*)&ob[8]  = *(const int4*)&st[lr][hf + 8];
  *(int4*)&ob[16] = *(const int4*)&st[lr][hf + 16];
  *(int4*)&ob[24] = *(const int4*)&st[lr][hf + 24];
}

// ================= segmented selective scan (256 thr = 16 ch x 16 states) =================

__global__ __launch_bounds__(256) void scan_pass1(
    const unsigned short* __restrict__ deltaT, const unsigned short* __restrict__ u2T,
    const unsigned short* __restrict__ xdbl,
    const float* __restrict__ A_log,
    float* __restrict__ hend, float* __restrict__ aprod)
{
  int t = threadIdx.x;
  int ch = t >> 4, n = t & 15;
  int li = (t & 15) * 4;
  int d0 = blockIdx.x * 16, d = d0 + ch;
  int base = blockIdx.y * SEGLEN;

  __shared__ __align__(16) float sdT[16][68], suT[16][68], sBT[16][68];

  float An = -__expf(A_log[d * DS + n]);

  ushort4 rdu = *(const ushort4*)&deltaT[(size_t)d * L_SEQ + base + li];
  ushort4 ru  = *(const ushort4*)&u2T[(size_t)d * L_SEQ + base + li];
  int llb = t >> 2;                 // 0..63
  int n4 = (t & 3) * 4;
  ushort4 rB = *(const ushort4*)&xdbl[(size_t)(base + llb) * 128 + 64 + n4];

  float d0v = bf2f(rdu.x), d1v = bf2f(rdu.y), d2v = bf2f(rdu.z), d3v = bf2f(rdu.w);
  sdT[ch][li + 0] = d0v; sdT[ch][li + 1] = d1v;
  sdT[ch][li + 2] = d2v; sdT[ch][li + 3] = d3v;
  suT[ch][li + 0] = d0v * bf2f(ru.x); suT[ch][li + 1] = d1v * bf2f(ru.y);
  suT[ch][li + 2] = d2v * bf2f(ru.z); suT[ch][li + 3] = d3v * bf2f(ru.w);
  sBT[n4 + 0][llb] = bf2f(rB.x); sBT[n4 + 1][llb] = bf2f(rB.y);
  sBT[n4 + 2][llb] = bf2f(rB.z); sBT[n4 + 3][llb] = bf2f(rB.w);
  __syncthreads();

  float h = 0.f, sdl = 0.f;
  #pragma unroll
  for (int g = 0; g < 64; g += 4) {
    float4 dl4 = *(const float4*)&sdT[ch][g];
    float4 du4 = *(const float4*)&suT[ch][g];
    float4 Bn4 = *(const float4*)&sBT[n][g];
    float dl[4] = {dl4.x, dl4.y, dl4.z, dl4.w};
    float du[4] = {du4.x, du4.y, du4.z, du4.w};
    float Bn[4] = {Bn4.x, Bn4.y, Bn4.z, Bn4.w};
    #pragma unroll
    for (int i = 0; i < 4; ++i) {
      float dA = __expf(dl[i] * An);
      sdl += dl[i];
      h = dA * h + du[i] * Bn[i];
    }
  }
  size_t idx = (size_t)blockIdx.y * NSTATE + d0 * DS + t;
  hend[idx]  = h;
  aprod[idx] = __expf(An * sdl);   // prod of exp == exp of sum
}

// ---- pass 2: prefix over segment summaries -> h_in ----
__global__ __launch_bounds__(256) void scan_pass2(
    const float* __restrict__ hend, const float* __restrict__ aprod,
    float* __restrict__ h_in)
{
  int i = blockIdx.x * 256 + threadIdx.x;
  float h = 0.f;
  h_in[i] = 0.f;
  for (int s = 0; s < NSEG - 1; ++s) {
    h = aprod[(size_t)s * NSTATE + i] * h + hend[(size_t)s * NSTATE + i];
    h_in[(size_t)(s + 1) * NSTATE + i] = h;
  }
}

// ---- pass 3: full scan per segment; writes yb [l][di] directly ----
#define SVP 262   // svh row stride in fp16 (131 dwords, coprime-ish banks)
__global__ __launch_bounds__(256) void scan_pass3(
    const unsigned short* __restrict__ deltaT, const unsigned short* __restrict__ u2T,
    const unsigned short* __restrict__ resT,
    const unsigned short* __restrict__ xdbl,
    const float* __restrict__ A_log, const float* __restrict__ Dp,
    const float* __restrict__ h_in,
    unsigned short* __restrict__ yb)
{
  int t = threadIdx.x;
  int ch = t >> 4, n = t & 15;
  int li = (t & 15) * 4;
  int d0 = blockIdx.x * 16, d = d0 + ch;
  int s = blockIdx.y;
  int base = s * SEGLEN;

  __shared__ __align__(16) float sdT[16][68], suT[16][68];
  __shared__ __align__(16) float sBT[16][68], sCT[16][68];
  __shared__ __align__(4) _Float16 svh[32][SVP];
  __shared__ __align__(16) unsigned short syt[32][16];

  float An = -__expf(A_log[d * DS + n]);
  float h = h_in[(size_t)s * NSTATE + d0 * DS + t];

  ushort4 rdu = *(const ushort4*)&deltaT[(size_t)d * L_SEQ + base + li];
  ushort4 ru  = *(const ushort4*)&u2T[(size_t)d * L_SEQ + base + li];
  int llb = t >> 2;                 // 0..63
  int n4 = (t & 3) * 4;
  ushort4 rB = *(const ushort4*)&xdbl[(size_t)(base + llb) * 128 + 64 + n4];
  ushort4 rC = *(const ushort4*)&xdbl[(size_t)(base + llb) * 128 + 80 + n4];

  float d0v = bf2f(rdu.x), d1v = bf2f(rdu.y), d2v = bf2f(rdu.z), d3v = bf2f(rdu.w);
  sdT[ch][li + 0] = d0v; sdT[ch][li + 1] = d1v;
  sdT[ch][li + 2] = d2v; sdT[ch][li + 3] = d3v;
  suT[ch][li + 0] = d0v * bf2f(ru.x); suT[ch][li + 1] = d1v * bf2f(ru.y);
  suT[ch][li + 2] = d2v * bf2f(ru.z); suT[ch][li + 3] = d3v * bf2f(ru.w);
  sBT[n4 + 0][llb] = bf2f(rB.x); sBT[n4 + 1][llb] = bf2f(rB.y);
  sBT[n4 + 2][llb] = bf2f(rB.z); sBT[n4 + 3][llb] = bf2f(rB.w);
  sCT[n4 + 0][llb] = bf2f(rC.x); sCT[n4 + 1][llb] = bf2f(rC.y);
  sCT[n4 + 2][llb] = bf2f(rC.z); sCT[n4 + 3][llb] = bf2f(rC.w);
  __syncthreads();

  #pragma unroll
  for (int half = 0; half < 2; ++half) {
    int g0 = half * 32;
    #pragma unroll
    for (int g = g0; g < g0 + 32; g += 4) {
      float4 dl4 = *(const float4*)&sdT[ch][g];
      float4 du4 = *(const float4*)&suT[ch][g];
      float4 Bn4 = *(const float4*)&sBT[n][g];
      float4 Cn4 = *(const float4*)&sCT[n][g];
      float dl[4] = {dl4.x, dl4.y, dl4.z, dl4.w};
      float du[4] = {du4.x, du4.y, du4.z, du4.w};
      float Bn[4] = {Bn4.x, Bn4.y, Bn4.z, Bn4.w};
      float Cn[4] = {Cn4.x, Cn4.y, Cn4.z, Cn4.w};
      #pragma unroll
      for (int i = 0; i < 4; ++i) {
        float dA = __expf(dl[i] * An);
        h = dA * h + du[i] * Bn[i];
        svh[g - g0 + i][t] = (_Float16)(h * Cn[i]);
      }
    }
    __syncthreads();

    // post-pass: 32 ll x 16 ch = 512 outputs / 256 threads
    #pragma unroll
    for (int r = 0; r < 2; ++r) {
      int idx = r * 256 + t;
      int ll = idx & 31, c2 = idx >> 5;   // c2 = channel 0..15
      const _Float16* row = &svh[ll][c2 * 16];
      float sum = 0.f;
      #pragma unroll
      for (int k = 0; k < 8; ++k) {
        h16x2 pv = *(const h16x2*)&row[k * 2];
        sum += (float)pv.x + (float)pv.y;
      }
      int dd = d0 + c2;
      int lg = base + g0 + ll;
      float uv = bf2f(u2T[(size_t)dd * L_SEQ + lg]);
      float rv = bf2f(resT[(size_t)dd * L_SEQ + lg]);
      float sig = 1.f / (1.f + __expf(-rv));
      syt[ll][c2] = f2bf((sum + uv * Dp[dd]) * rv * sig);
    }
    __syncthreads();
    if (t < 64) {
      int lr = t >> 1, hf = (t & 1) * 8;
      int lg = base + g0 + lr;
      *(int4*)&yb[(size_t)lg * DI + d0 + hf] = *(const int4*)&syt[lr][hf];
    }
    __syncthreads();
  }
}

// ---------------- launch ----------------
extern "C" void kernel_launch(void* const* d_in, const int* in_sizes, int n_in,
                              void* d_out, int out_size, void* d_ws, size_t ws_size,
                              hipStream_t stream)
{
  const float* x      = (const float*)d_in[0];
  const float* W_in   = (const float*)d_in[1];
  const float* W_conv = (const float*)d_in[2];
  const float* b_conv = (const float*)d_in[3];
  const float* W_x    = (const float*)d_in[4];
  const float* W_dt   = (const float*)d_in[5];
  const float* b_dt   = (const float*)d_in[6];
  const float* A_log  = (const float*)d_in[7];
  const float* Dp     = (const float*)d_in[8];
  const float* W_out  = (const float*)d_in[9];
  const float* ln_s   = (const float*)d_in[10];
  const float* ln_b   = (const float*)d_in[11];

  char* ws = (char*)d_ws;
  const size_t MB = 1u << 20;
  unsigned short* xnb    = (unsigned short*)(ws);               // 0-4
  unsigned short* xrT    = (unsigned short*)(ws + 4 * MB);      // 4-20: bf16 [4096][2048]
  unsigned short* u2T    = (unsigned short*)(ws + 20 * MB);     // 20-28
  unsigned short* u2b    = (unsigned short*)(ws + 28 * MB);     // 28-36 (dead after xdbl gemm)
  float*          hend   = (float*)(ws + 28 * MB);              // 4 MB, aliases u2b
  float*          aprod  = (float*)(ws + 32 * MB);              // 4 MB, aliases u2b
  unsigned short* xdbl   = (unsigned short*)(ws + 36 * MB);     // 0.5 MB
  unsigned short* Wxt    = (unsigned short*)(ws + 36 * MB + 512 * 1024); // 0.5 MB
  unsigned short* Wdt_t  = (unsigned short*)(ws + 37 * MB);     // 0.25 MB
  unsigned short* deltaTb= (unsigned short*)(ws + 38 * MB);     // 38-46: bf16 [2048][2048]
  unsigned short* Wtin   = (unsigned short*)(ws + 38 * MB);     // aliases deltaTb (dead before delta GEMM)
  float*          part   = (float*)(ws + 46 * MB);              // 46-54: xdbl split-K partials (8 MB)
  float*          h_in   = (float*)(ws + 62 * MB);              // 62-66
  unsigned short* Wtout  = (unsigned short*)(ws + 66 * MB);     // 66-70
  unsigned short* yb     = (unsigned short*)(ws + 4 * MB);      // aliases dead u-rows of xrT
  const unsigned short* resT = xrT + (size_t)DI * L_SEQ;        // rows [2048,4096)

  prep_all<<<3632, 256, 0, stream>>>(x, ln_s, ln_b, xnb,
                                     W_in, W_out, W_dt, W_x,
                                     Wtin, Wtout, Wdt_t, Wxt);

  gemm2<128, 128, 0, 1, 1, 1><<<dim3(L_SEQ / 128, (2 * DI) / 128), 256, 0, stream>>>(
      Wtin, DM, xnb, DM, xrT, L_SEQ, 2 * DI, L_SEQ, DM, nullptr, nullptr, 0);

  conv_silu_fused<<<dim3(DI / 64, L_SEQ / 128), 256, 0, stream>>>(
      xrT, W_conv, b_conv, u2T, u2b);

  gemm2<64, 128, 0, 0, 8, 1><<<dim3(1, L_SEQ / 64, 8), 256, 0, stream>>>(
      u2b, DI, Wxt, DI, part, 128, L_SEQ, 128, DI, nullptr, nullptr, 0);

  xdbl_reduce<<<(L_SEQ * 128) / 1024, 256, 0, stream>>>(part, xdbl);

  gemm2<64, 128, 1, 1, 1, 0><<<dim3(L_SEQ / 128, DI / 64), 256, 0, stream>>>(
      Wdt_t, DTR, xdbl, 128, deltaTb, L_SEQ, DI, L_SEQ, DTR, b_dt, nullptr, 0);

  scan_pass1<<<dim3(DI / 16, NSEG - 1), 256, 0, stream>>>(
      deltaTb, u2T, xdbl, A_log, hend, aprod);

  scan_pass2<<<NSTATE / 256, 256, 0, stream>>>(hend, aprod, h_in);

  scan_pass3<<<dim3(DI / 16, NSEG), 256, 0, stream>>>(
      deltaTb, u2T, resT, xdbl, A_log, Dp, h_in, yb);

  // final: out = y @ W_out + x, split-K=1, fused residual epilogue, deep pipeline
  gemm2<64, 64, 2, 0, 1, 1><<<dim3(DM / 64, L_SEQ / 64), 256, 0, stream>>>(
      yb, DI, Wtout, DI, (float*)d_out, DM, L_SEQ, DM, DI, nullptr, x, DM);
}